// Round 9
// baseline (62.546 us; speedup 1.0000x reference)
//
#include <hip/hip_runtime.h>
#include <hip/hip_fp16.h>

#define BATCH 8
#define CH 3
#define H_OUT 384
#define W_OUT 1280
#define H_IN 96
#define W_IN 320
#define HW_OUT (H_OUT * W_OUT)
#define HW_IN (H_IN * W_IN)

#define ROWS_PT 2
#define SEGS_PER_ROW (W_OUT / 256)           // 5
#define PAIRS (H_OUT / ROWS_PT)              // 192
#define CHUNKS_PER_B (PAIRS * SEGS_PER_ROW)  // 960

#define LCOLS 68
#define LROWS 3

// MODE1 fallback: single-row packed fp16x4, 8 B/px, stride 1282, 1-px front pad
#define P1STRIDE 1282
#define P1_HALVES ((size_t)(1 + (size_t)BATCH * H_OUT * P1STRIDE) * 4)
#define P1_BYTES (P1_HALVES * 2)

// MODE2: row-pair packed. entry(e,cxi) = 16B fp16x8:
//   first half  = image row e-1 {c0,c1,c2,0}  (zeros if e==0)
//   second half = image row e   {c0,c1,c2,0}  (zeros if e==H_OUT)
// cols: cxi=0 ghost(x=-1, zeros), cxi=1..1280 -> x=cxi-1, cxi=1281 ghost(x=1280, zeros)
#define RP_STRIDE 1282
#define RP_ROWS (H_OUT + 1)                  // entries e = 0..384
#define RP_EPB ((size_t)RP_ROWS * RP_STRIDE)
#define RP_ENTRIES ((size_t)BATCH * RP_EPB)
#define RP_BYTES (RP_ENTRIES * 16)           // ~63.2 MB

struct __attribute__((packed, aligned(4))) f2 { float x, y; };
struct __attribute__((packed, aligned(8))) h8 { unsigned int w[4]; };
struct __attribute__((aligned(16))) h16 { unsigned int w[4]; };

static __device__ __forceinline__ __half2 u2h2(unsigned int u) {
    return *reinterpret_cast<__half2*>(&u);
}

// ---------------- MODE2 pack: planar f32 -> row-pair fp16x8 entries ----------------
__global__ __launch_bounds__(256) void pack_rowpair_kernel(
    const float* __restrict__ image, __half* __restrict__ pk)
{
    size_t i = (size_t)blockIdx.x * 256 + threadIdx.x;
    if (i >= RP_ENTRIES) return;
    int b = (int)(i / RP_EPB);
    int rem = (int)(i - (size_t)b * RP_EPB);
    int e = rem / RP_STRIDE;
    int cxi = rem - e * RP_STRIDE;
    int x = cxi - 1;

    __half2 p0 = __floats2half2_rn(0.0f, 0.0f);
    __half2 p1 = p0, p2 = p0, p3 = p0;
    if (x >= 0 && x < W_OUT) {
        const float* ib = image + (size_t)b * (CH * HW_OUT);
        int y0 = e - 1, y1 = e;
        if (y0 >= 0) {
            int o = y0 * W_OUT + x;
            p0 = __floats2half2_rn(ib[o], ib[HW_OUT + o]);
            p1 = __floats2half2_rn(ib[2 * HW_OUT + o], 0.0f);
        }
        if (y1 < H_OUT) {
            int o = y1 * W_OUT + x;
            p2 = __floats2half2_rn(ib[o], ib[HW_OUT + o]);
            p3 = __floats2half2_rn(ib[2 * HW_OUT + o], 0.0f);
        }
    }
    h16 v;
    v.w[0] = *reinterpret_cast<unsigned int*>(&p0);
    v.w[1] = *reinterpret_cast<unsigned int*>(&p1);
    v.w[2] = *reinterpret_cast<unsigned int*>(&p2);
    v.w[3] = *reinterpret_cast<unsigned int*>(&p3);
    *reinterpret_cast<h16*>(pk + i * 8) = v;
}

// ---------------- MODE1 pack (fallback): single-row fp16x4 ----------------
__global__ __launch_bounds__(256) void pack_single_kernel(
    const float* __restrict__ image, __half* __restrict__ pk)
{
    int i = blockIdx.x * 256 + threadIdx.x;
    int b = i / HW_OUT;
    int p = i - b * HW_OUT;
    int y = p / W_OUT;
    int x = p - y * W_OUT;
    const float* ib = image + (size_t)b * (CH * HW_OUT) + p;
    __half2 lo = __floats2half2_rn(ib[0], ib[HW_OUT]);
    __half2 hi = __floats2half2_rn(ib[2 * HW_OUT], 0.0f);
    uint2 v;
    v.x = *reinterpret_cast<unsigned int*>(&lo);
    v.y = *reinterpret_cast<unsigned int*>(&hi);
    __half* pd = pk + 4;
    size_t row = (size_t)b * H_OUT + y;
    *reinterpret_cast<uint2*>(pd + (row * P1STRIDE + x) * 4) = v;
    if (i < BATCH * H_OUT) {
        uint2 z; z.x = 0u; z.y = 0u;
        size_t r = (size_t)i;
        *reinterpret_cast<uint2*>(pd + (r * P1STRIDE + 1280) * 4) = z;
        *reinterpret_cast<uint2*>(pd + (r * P1STRIDE + 1281) * 4) = z;
        if (i == 0) *reinterpret_cast<uint2*>(pk) = z;
    }
}

// ---------------- main kernel ----------------
template <int MODE>   // 0 = planar f32, 1 = single-row packed, 2 = row-pair packed
__global__ __launch_bounds__(256) void warp_sceneflow_kernel(
    const float* __restrict__ image,
    const __half* __restrict__ pk,
    const float* __restrict__ disp,
    const float* __restrict__ scene,
    const float* __restrict__ intrin,
    const float* __restrict__ aug,
    float* __restrict__ out)
{
    int bid = blockIdx.x;
    int b = bid & 7;                   // XCD-pinned batch
    int c = bid >> 3;
    int yp = c / SEGS_PER_ROW;
    int xseg = c - yp * SEGS_PER_ROW;
    int x = xseg * 256 + threadIdx.x;
    int ybase = yp * ROWS_PT;

    __shared__ float4 lds4[LROWS][LCOLS];
    int ylo = (int)((float)ybase * ((float)(H_IN - 1) / (float)(H_OUT - 1)));
    int xlo = (int)((float)(xseg * 256) * ((float)(W_IN - 1) / (float)(W_OUT - 1)));
    if (threadIdx.x < LROWS * LCOLS) {
        int row = threadIdx.x / LCOLS;
        int col = threadIdx.x - row * LCOLS;
        int gy = min(ylo + row, H_IN - 1);
        int gx = min(xlo + col, W_IN - 1);
        int gi = gy * W_IN + gx;
        const float* dp = disp + b * HW_IN;
        const float* sp = scene + b * (CH * HW_IN);
        float4 v;
        v.x = dp[gi];
        v.y = sp[gi];
        v.z = sp[HW_IN + gi];
        v.w = sp[2 * HW_IN + gi];
        lds4[row][col] = v;
    }
    __syncthreads();

    float sy = (float)H_OUT / aug[b * 2 + 0];
    float sxs = (float)W_OUT / aug[b * 2 + 1];
    float fx = intrin[b * 9 + 0] * sxs;
    float fy = intrin[b * 9 + 4] * sy;
    float cx = intrin[b * 9 + 2] * sxs;
    float cy = intrin[b * 9 + 5] * sy;
    float inv_fx = 1.0f / fx;
    float inv_fy = 1.0f / fy;

    float xsrc = (float)x * ((float)(W_IN - 1) / (float)(W_OUT - 1));
    int x0 = (int)xsrc;
    float wx = xsrc - (float)x0;
    int lx = x0 - xlo;

    float g00[ROWS_PT], g01[ROWS_PT], g10[ROWS_PT], g11[ROWS_PT];
    int rb0[ROWS_PT], rb1[ROWS_PT];
    bool rc[ROWS_PT], lc[ROWS_PT];   // planar fallback only

    #pragma unroll
    for (int r = 0; r < ROWS_PT; ++r) {
        int y = ybase + r;
        float ysrc = (float)y * ((float)(H_IN - 1) / (float)(H_OUT - 1));
        int y0 = (int)ysrc;
        float wy = ysrc - (float)y0;
        int ly = y0 - ylo;

        float4 t00 = lds4[ly][lx];
        float4 t01 = lds4[ly][lx + 1];
        float4 t10 = lds4[ly + 1][lx];
        float4 t11 = lds4[ly + 1][lx + 1];

        float w00 = (1.0f - wy) * (1.0f - wx);
        float w01 = (1.0f - wy) * wx;
        float w10 = wy * (1.0f - wx);
        float w11 = wy * wx;

        float dval = w00 * t00.x + w01 * t01.x + w10 * t10.x + w11 * t11.x;
        float sc0  = w00 * t00.y + w01 * t01.y + w10 * t10.y + w11 * t11.y;
        float sc1  = w00 * t00.z + w01 * t01.z + w10 * t10.z + w11 * t11.z;
        float sc2  = w00 * t00.w + w01 * t01.w + w10 * t10.w + w11 * t11.w;

        float disp_full = dval * (float)W_OUT;
        float depth = fminf(fmaxf(fx * 0.54f / (disp_full + 1e-8f), 0.001f), 80.0f);

        float X = ((float)x - cx) * inv_fx * depth + sc0;
        float Y = ((float)y - cy) * inv_fy * depth + sc1;
        float Z = depth + sc2;
        float u = fx * X + cx * Z;
        float v = fy * Y + cy * Z;
        float rw = 1.0f / (Z + 1e-8f);
        float gx = u * rw;              // normalize round-trip elided (exact)
        float gy = v * rw;

        float gx0f = floorf(gx), gy0f = floorf(gy);
        float fwx = gx - gx0f, fwy = gy - gy0f;
        int ix0 = (int)gx0f, iy0 = (int)gy0f;
        int ix1 = ix0 + 1, iy1 = iy0 + 1;
        bool vx0 = (ix0 >= 0) && (ix0 <= W_OUT - 1);
        bool vx1 = (ix1 >= 0) && (ix1 <= W_OUT - 1);
        bool vy0 = (iy0 >= 0) && (iy0 <= H_OUT - 1);
        bool vy1 = (iy1 >= 0) && (iy1 <= H_OUT - 1);
        g00[r] = (1.0f - fwy) * (1.0f - fwx) * ((vx0 && vy0) ? 1.0f : 0.0f);
        g01[r] = (1.0f - fwy) * fwx * ((vx1 && vy0) ? 1.0f : 0.0f);
        g10[r] = fwy * (1.0f - fwx) * ((vx0 && vy1) ? 1.0f : 0.0f);
        g11[r] = fwy * fwx * ((vx1 && vy1) ? 1.0f : 0.0f);

        if constexpr (MODE == 2) {
            int e   = min(max(iy0 + 1, 0), H_OUT);     // 0..384
            int cxi = min(max(ix0 + 1, 0), W_OUT);     // 0..1280; x1 tap = cxi+1 <= 1281
            rb0[r] = (b * RP_ROWS + e) * RP_STRIDE + cxi;
            rb1[r] = 0;
        } else if constexpr (MODE == 1) {
            int cy0 = min(max(iy0, 0), H_OUT - 1);
            int cy1 = min(max(iy1, 0), H_OUT - 1);
            int bx = min(max(ix0, -1), W_OUT - 1);
            rb0[r] = ((b * H_OUT + cy0) * P1STRIDE + bx);
            rb1[r] = ((b * H_OUT + cy1) * P1STRIDE + bx);
        } else {
            int cy0 = min(max(iy0, 0), H_OUT - 1);
            int cy1 = min(max(iy1, 0), H_OUT - 1);
            int cx0 = min(max(ix0, 0), W_OUT - 1);
            int cx1 = min(max(ix1, 0), W_OUT - 1);
            int xbi = min(cx0, W_OUT - 2);
            rc[r] = (cx0 != xbi);
            lc[r] = (cx1 == xbi);
            rb0[r] = cy0 * W_OUT + xbi;
            rb1[r] = cy1 * W_OUT + xbi;
        }
    }

    float res[ROWS_PT][CH];
    if constexpr (MODE == 2) {
        #pragma unroll
        for (int r = 0; r < ROWS_PT; ++r) {
            // L0: {v00, v10}, L1: {v01, v11} — same packed row entry, 16B apart
            h16 L0 = *reinterpret_cast<const h16*>(pk + (size_t)rb0[r] * 8);
            h16 L1 = *reinterpret_cast<const h16*>(pk + (size_t)rb0[r] * 8 + 8);
            __half2 G00 = __float2half2_rn(g00[r]);
            __half2 G01 = __float2half2_rn(g01[r]);
            __half2 G10 = __float2half2_rn(g10[r]);
            __half2 G11 = __float2half2_rn(g11[r]);
            __half2 acc01 = __hmul2(G00, u2h2(L0.w[0]));
            acc01 = __hfma2(G10, u2h2(L0.w[2]), acc01);
            acc01 = __hfma2(G01, u2h2(L1.w[0]), acc01);
            acc01 = __hfma2(G11, u2h2(L1.w[2]), acc01);
            __half2 acc2 = __hmul2(G00, u2h2(L0.w[1]));
            acc2 = __hfma2(G10, u2h2(L0.w[3]), acc2);
            acc2 = __hfma2(G01, u2h2(L1.w[1]), acc2);
            acc2 = __hfma2(G11, u2h2(L1.w[3]), acc2);
            float2 f01 = __half22float2(acc01);
            res[r][0] = f01.x;
            res[r][1] = f01.y;
            res[r][2] = __low2float(acc2);
        }
    } else if constexpr (MODE == 1) {
        const __half* pd = pk + 4;
        #pragma unroll
        for (int r = 0; r < ROWS_PT; ++r) {
            h8 L0 = *reinterpret_cast<const h8*>(pd + (size_t)rb0[r] * 4);
            h8 L1 = *reinterpret_cast<const h8*>(pd + (size_t)rb1[r] * 4);
            __half2 h0a = u2h2(L0.w[0]), h0b = u2h2(L0.w[1]);
            __half2 h1a = u2h2(L0.w[2]), h1b = u2h2(L0.w[3]);
            __half2 k0a = u2h2(L1.w[0]), k0b = u2h2(L1.w[1]);
            __half2 k1a = u2h2(L1.w[2]), k1b = u2h2(L1.w[3]);
            res[r][0] = g00[r] * __low2float(h0a) + g01[r] * __low2float(h1a)
                      + g10[r] * __low2float(k0a) + g11[r] * __low2float(k1a);
            res[r][1] = g00[r] * __high2float(h0a) + g01[r] * __high2float(h1a)
                      + g10[r] * __high2float(k0a) + g11[r] * __high2float(k1a);
            res[r][2] = g00[r] * __low2float(h0b) + g01[r] * __low2float(h1b)
                      + g10[r] * __low2float(k0b) + g11[r] * __low2float(k1b);
        }
    } else {
        const float* ib = image + (size_t)b * (CH * HW_OUT);
        const float* im0 = ib;
        const float* im1 = ib + HW_OUT;
        const float* im2 = ib + 2 * HW_OUT;
        #pragma unroll
        for (int r = 0; r < ROWS_PT; ++r) {
            f2 P0 = *(const f2*)(im0 + rb0[r]); f2 P1 = *(const f2*)(im0 + rb1[r]);
            f2 Q0 = *(const f2*)(im1 + rb0[r]); f2 Q1 = *(const f2*)(im1 + rb1[r]);
            f2 T0 = *(const f2*)(im2 + rb0[r]); f2 T1 = *(const f2*)(im2 + rb1[r]);
            float p00 = rc[r] ? P0.y : P0.x, p01 = lc[r] ? P0.x : P0.y;
            float p10 = rc[r] ? P1.y : P1.x, p11 = lc[r] ? P1.x : P1.y;
            float q00 = rc[r] ? Q0.y : Q0.x, q01 = lc[r] ? Q0.x : Q0.y;
            float q10 = rc[r] ? Q1.y : Q1.x, q11 = lc[r] ? Q1.x : Q1.y;
            float t00 = rc[r] ? T0.y : T0.x, t01 = lc[r] ? T0.x : T0.y;
            float t10 = rc[r] ? T1.y : T1.x, t11 = lc[r] ? T1.x : T1.y;
            res[r][0] = g00[r] * p00 + g01[r] * p01 + g10[r] * p10 + g11[r] * p11;
            res[r][1] = g00[r] * q00 + g01[r] * q01 + g10[r] * q10 + g11[r] * q11;
            res[r][2] = g00[r] * t00 + g01[r] * t01 + g10[r] * t10 + g11[r] * t11;
        }
    }

    float* ob = out + (size_t)b * (CH * HW_OUT);
    #pragma unroll
    for (int r = 0; r < ROWS_PT; ++r) {
        int op = (ybase + r) * W_OUT + x;
        __builtin_nontemporal_store(res[r][0], ob + op);
        __builtin_nontemporal_store(res[r][1], ob + HW_OUT + op);
        __builtin_nontemporal_store(res[r][2], ob + 2 * HW_OUT + op);
    }
}

extern "C" void kernel_launch(void* const* d_in, const int* in_sizes, int n_in,
                              void* d_out, int out_size, void* d_ws, size_t ws_size,
                              hipStream_t stream) {
    const float* image  = (const float*)d_in[0];
    const float* disp   = (const float*)d_in[1];
    const float* scene  = (const float*)d_in[2];
    const float* intrin = (const float*)d_in[3];
    const float* aug    = (const float*)d_in[4];
    float* out = (float*)d_out;

    const int grid = BATCH * CHUNKS_PER_B;  // 7680 blocks

    if (ws_size >= RP_BYTES) {
        __half* pk = (__half*)d_ws;
        const int pgrid = (int)((RP_ENTRIES + 255) / 256);
        pack_rowpair_kernel<<<pgrid, 256, 0, stream>>>(image, pk);
        warp_sceneflow_kernel<2><<<grid, 256, 0, stream>>>(
            image, pk, disp, scene, intrin, aug, out);
    } else if (ws_size >= P1_BYTES) {
        __half* pk = (__half*)d_ws;
        pack_single_kernel<<<BATCH * HW_OUT / 256, 256, 0, stream>>>(image, pk);
        warp_sceneflow_kernel<1><<<grid, 256, 0, stream>>>(
            image, pk, disp, scene, intrin, aug, out);
    } else {
        warp_sceneflow_kernel<0><<<grid, 256, 0, stream>>>(
            image, nullptr, disp, scene, intrin, aug, out);
    }
}

// Round 10
// 52.118 us; speedup vs baseline: 1.2001x; 1.2001x over previous
//
#include <hip/hip_runtime.h>
#include <hip/hip_fp16.h>

#define BATCH 8
#define CH 3
#define H_OUT 384
#define W_OUT 1280
#define H_IN 96
#define W_IN 320
#define HW_OUT (H_OUT * W_OUT)
#define HW_IN (H_IN * W_IN)

// block = 256 threads = 4 waves; each WAVE covers a 16x * 4y tile,
// block covers 64x * 4y. Grid = 8b * 96ys * 20xs = 15360.
#define XS_PER_ROW 20
#define YSEGS (H_OUT / 4)                 // 96
#define CHUNKS_PER_B (YSEGS * XS_PER_ROW) // 1920

#define LCOLS 18
#define LROWS 3

// packed image: single-row fp16x4 {c0,c1,c2,0}, 8 B/px, stride 1282,
// 1-px front pad (base can be -1), ghost cols 1280/1281 zeroed. 3.95 MB/batch -> fits XCD L2.
#define P1STRIDE 1282
#define P1_HALVES ((size_t)(1 + (size_t)BATCH * H_OUT * P1STRIDE) * 4)
#define P1_BYTES (P1_HALVES * 2)

struct __attribute__((packed, aligned(4))) f2 { float x, y; };
struct __attribute__((packed, aligned(8))) h8 { unsigned int w[4]; };

static __device__ __forceinline__ __half2 u2h2(unsigned int u) {
    return *reinterpret_cast<__half2*>(&u);
}

// ---------------- pack: planar f32 -> strided interleaved fp16x4 ----------------
__global__ __launch_bounds__(256) void pack_single_kernel(
    const float* __restrict__ image, __half* __restrict__ pk)
{
    int i = blockIdx.x * 256 + threadIdx.x;   // B*HW_OUT threads exactly
    int b = i / HW_OUT;
    int p = i - b * HW_OUT;
    int y = p / W_OUT;
    int x = p - y * W_OUT;
    const float* ib = image + (size_t)b * (CH * HW_OUT) + p;
    __half2 lo = __floats2half2_rn(ib[0], ib[HW_OUT]);
    __half2 hi = __floats2half2_rn(ib[2 * HW_OUT], 0.0f);
    uint2 v;
    v.x = *reinterpret_cast<unsigned int*>(&lo);
    v.y = *reinterpret_cast<unsigned int*>(&hi);
    __half* pd = pk + 4;
    size_t row = (size_t)b * H_OUT + y;
    *reinterpret_cast<uint2*>(pd + (row * P1STRIDE + x) * 4) = v;
    if (i < BATCH * H_OUT) {
        uint2 z; z.x = 0u; z.y = 0u;
        size_t r = (size_t)i;
        *reinterpret_cast<uint2*>(pd + (r * P1STRIDE + 1280) * 4) = z;
        *reinterpret_cast<uint2*>(pd + (r * P1STRIDE + 1281) * 4) = z;
        if (i == 0) *reinterpret_cast<uint2*>(pk) = z;
    }
}

// ---------------- main kernel: 16x4 wave tiles ----------------
template <int MODE>   // 0 = planar f32 gathers, 1 = packed fp16x4 gathers
__global__ __launch_bounds__(256) void warp_sceneflow_kernel(
    const float* __restrict__ image,
    const __half* __restrict__ pk,
    const float* __restrict__ disp,
    const float* __restrict__ scene,
    const float* __restrict__ intrin,
    const float* __restrict__ aug,
    float* __restrict__ out)
{
    int bid = blockIdx.x;
    int b = bid & 7;                     // XCD-pinned batch
    int c = bid >> 3;                    // 0..1919
    int ys = c / XS_PER_ROW;
    int xs = c - ys * XS_PER_ROW;
    int ybase = ys * 4;
    int xbase = xs * 64;

    int tid = threadIdx.x;
    int wave = tid >> 6;                 // 0..3
    int lane = tid & 63;
    int lx16 = lane & 15;
    int ly4  = lane >> 4;                // 0..3
    int x = xbase + wave * 16 + lx16;    // wave footprint: 16 x * 4 y
    int y = ybase + ly4;

    // interleaved low-res LDS tile {disp,s0,s1,s2}
    __shared__ float4 lds4[LROWS][LCOLS];
    int ylo = (int)((float)ybase * ((float)(H_IN - 1) / (float)(H_OUT - 1)));
    int xlo = (int)((float)xbase * ((float)(W_IN - 1) / (float)(W_OUT - 1)));
    if (tid < LROWS * LCOLS) {
        int row = tid / LCOLS;
        int col = tid - row * LCOLS;
        int gy = min(ylo + row, H_IN - 1);
        int gx = min(xlo + col, W_IN - 1);
        int gi = gy * W_IN + gx;
        const float* dp = disp + b * HW_IN;
        const float* sp = scene + b * (CH * HW_IN);
        float4 v;
        v.x = dp[gi];
        v.y = sp[gi];
        v.z = sp[HW_IN + gi];
        v.w = sp[2 * HW_IN + gi];
        lds4[row][col] = v;
    }
    __syncthreads();

    float syr = (float)H_OUT / aug[b * 2 + 0];
    float sxr = (float)W_OUT / aug[b * 2 + 1];
    float fx = intrin[b * 9 + 0] * sxr;
    float fy = intrin[b * 9 + 4] * syr;
    float cx = intrin[b * 9 + 2] * sxr;
    float cy = intrin[b * 9 + 5] * syr;
    float inv_fx = 1.0f / fx;
    float inv_fy = 1.0f / fy;

    // low-res bilinear (all from LDS)
    float xsrc = (float)x * ((float)(W_IN - 1) / (float)(W_OUT - 1));
    int x0 = (int)xsrc;
    float wx = xsrc - (float)x0;
    int lx = x0 - xlo;

    float ysrc = (float)y * ((float)(H_IN - 1) / (float)(H_OUT - 1));
    int y0 = (int)ysrc;
    float wy = ysrc - (float)y0;
    int ly = y0 - ylo;

    float4 t00 = lds4[ly][lx];
    float4 t01 = lds4[ly][lx + 1];
    float4 t10 = lds4[ly + 1][lx];
    float4 t11 = lds4[ly + 1][lx + 1];

    float w00 = (1.0f - wy) * (1.0f - wx);
    float w01 = (1.0f - wy) * wx;
    float w10 = wy * (1.0f - wx);
    float w11 = wy * wx;

    float dval = w00 * t00.x + w01 * t01.x + w10 * t10.x + w11 * t11.x;
    float sc0  = w00 * t00.y + w01 * t01.y + w10 * t10.y + w11 * t11.y;
    float sc1  = w00 * t00.z + w01 * t01.z + w10 * t10.z + w11 * t11.z;
    float sc2  = w00 * t00.w + w01 * t01.w + w10 * t10.w + w11 * t11.w;

    float disp_full = dval * (float)W_OUT;
    float depth = fminf(fmaxf(fx * 0.54f / (disp_full + 1e-8f), 0.001f), 80.0f);

    float X = ((float)x - cx) * inv_fx * depth + sc0;
    float Y = ((float)y - cy) * inv_fy * depth + sc1;
    float Z = depth + sc2;
    float u = fx * X + cx * Z;
    float v = fy * Y + cy * Z;
    float rw = 1.0f / (Z + 1e-8f);
    float gx = u * rw;                   // normalize round-trip elided (exact)
    float gy = v * rw;

    int ix0 = __float2int_rd(gx);
    int iy0 = __float2int_rd(gy);
    float fwx = gx - (float)ix0;
    float fwy = gy - (float)iy0;
    int ix1 = ix0 + 1, iy1 = iy0 + 1;
    bool vx0 = (ix0 >= 0) && (ix0 <= W_OUT - 1);
    bool vx1 = (ix1 >= 0) && (ix1 <= W_OUT - 1);
    bool vy0 = (iy0 >= 0) && (iy0 <= H_OUT - 1);
    bool vy1 = (iy1 >= 0) && (iy1 <= H_OUT - 1);
    float g00 = (1.0f - fwy) * (1.0f - fwx) * ((vx0 && vy0) ? 1.0f : 0.0f);
    float g01 = (1.0f - fwy) * fwx * ((vx1 && vy0) ? 1.0f : 0.0f);
    float g10 = fwy * (1.0f - fwx) * ((vx0 && vy1) ? 1.0f : 0.0f);
    float g11 = fwy * fwx * ((vx1 && vy1) ? 1.0f : 0.0f);
    int cy0 = min(max(iy0, 0), H_OUT - 1);
    int cy1 = min(max(iy1, 0), H_OUT - 1);

    float r0, r1, r2;
    if constexpr (MODE == 1) {
        int bx = min(max(ix0, -1), W_OUT - 1);
        const __half* pd = pk + 4;
        size_t rb0 = ((size_t)(b * H_OUT + cy0) * P1STRIDE + bx);
        size_t rb1 = ((size_t)(b * H_OUT + cy1) * P1STRIDE + bx);
        h8 L0 = *reinterpret_cast<const h8*>(pd + rb0 * 4);
        h8 L1 = *reinterpret_cast<const h8*>(pd + rb1 * 4);
        __half2 h0a = u2h2(L0.w[0]), h0b = u2h2(L0.w[1]);   // x0: c0c1 / c2
        __half2 h1a = u2h2(L0.w[2]), h1b = u2h2(L0.w[3]);   // x1
        __half2 k0a = u2h2(L1.w[0]), k0b = u2h2(L1.w[1]);   // row y1
        __half2 k1a = u2h2(L1.w[2]), k1b = u2h2(L1.w[3]);
        r0 = g00 * __low2float(h0a) + g01 * __low2float(h1a)
           + g10 * __low2float(k0a) + g11 * __low2float(k1a);
        r1 = g00 * __high2float(h0a) + g01 * __high2float(h1a)
           + g10 * __high2float(k0a) + g11 * __high2float(k1a);
        r2 = g00 * __low2float(h0b) + g01 * __low2float(h1b)
           + g10 * __low2float(k0b) + g11 * __low2float(k1b);
    } else {
        int cx0 = min(max(ix0, 0), W_OUT - 1);
        int cx1 = min(max(ix1, 0), W_OUT - 1);
        int xbi = min(cx0, W_OUT - 2);
        bool rcf = (cx0 != xbi);
        bool lcf = (cx1 == xbi);
        int rb0 = cy0 * W_OUT + xbi;
        int rb1 = cy1 * W_OUT + xbi;
        const float* ib = image + (size_t)b * (CH * HW_OUT);
        const float* im0 = ib;
        const float* im1 = ib + HW_OUT;
        const float* im2 = ib + 2 * HW_OUT;
        f2 P0 = *(const f2*)(im0 + rb0); f2 P1 = *(const f2*)(im0 + rb1);
        f2 Q0 = *(const f2*)(im1 + rb0); f2 Q1 = *(const f2*)(im1 + rb1);
        f2 T0 = *(const f2*)(im2 + rb0); f2 T1 = *(const f2*)(im2 + rb1);
        float p00 = rcf ? P0.y : P0.x, p01 = lcf ? P0.x : P0.y;
        float p10 = rcf ? P1.y : P1.x, p11 = lcf ? P1.x : P1.y;
        float q00 = rcf ? Q0.y : Q0.x, q01 = lcf ? Q0.x : Q0.y;
        float q10 = rcf ? Q1.y : Q1.x, q11 = lcf ? Q1.x : Q1.y;
        float t00f = rcf ? T0.y : T0.x, t01f = lcf ? T0.x : T0.y;
        float t10f = rcf ? T1.y : T1.x, t11f = lcf ? T1.x : T1.y;
        r0 = g00 * p00 + g01 * p01 + g10 * p10 + g11 * p11;
        r1 = g00 * q00 + g01 * q01 + g10 * q10 + g11 * q11;
        r2 = g00 * t00f + g01 * t01f + g10 * t10f + g11 * t11f;
    }

    float* ob = out + (size_t)b * (CH * HW_OUT);
    int op = y * W_OUT + x;
    __builtin_nontemporal_store(r0, ob + op);
    __builtin_nontemporal_store(r1, ob + HW_OUT + op);
    __builtin_nontemporal_store(r2, ob + 2 * HW_OUT + op);
}

extern "C" void kernel_launch(void* const* d_in, const int* in_sizes, int n_in,
                              void* d_out, int out_size, void* d_ws, size_t ws_size,
                              hipStream_t stream) {
    const float* image  = (const float*)d_in[0];
    const float* disp   = (const float*)d_in[1];
    const float* scene  = (const float*)d_in[2];
    const float* intrin = (const float*)d_in[3];
    const float* aug    = (const float*)d_in[4];
    float* out = (float*)d_out;

    const int grid = BATCH * CHUNKS_PER_B;  // 15360 blocks

    if (ws_size >= P1_BYTES) {
        __half* pk = (__half*)d_ws;
        pack_single_kernel<<<BATCH * HW_OUT / 256, 256, 0, stream>>>(image, pk);
        warp_sceneflow_kernel<1><<<grid, 256, 0, stream>>>(
            image, pk, disp, scene, intrin, aug, out);
    } else {
        warp_sceneflow_kernel<0><<<grid, 256, 0, stream>>>(
            image, nullptr, disp, scene, intrin, aug, out);
    }
}